// Round 1
// baseline (210.482 us; speedup 1.0000x reference)
//
#include <hip/hip_runtime.h>
#include <hip/hip_bf16.h>

// Problem constants (B, S, NK, H, D, DM) = (2, 2048, 32, 8, 64, 512)
constexpr int Bb  = 2;
constexpr int Ss  = 2048;
constexpr int NKk = 32;
constexpr int Hh  = 8;
constexpr int Dd  = 64;
constexpr int DMm = 512;
constexpr int Mm  = Bb * Ss;   // 4096 rows

// ---------------------------------------------------------------------------
// Tiled fp32 GEMM: Y = X @ W  (+ bias[n] + resid[m][n] if bias != nullptr)
// X: (M, 512) row-major, W: (512, 512) row-major, Y: (M, 512)
// 64x64 output tile per block, BK=16, 256 threads, 4x4 register micro-tile.
// ---------------------------------------------------------------------------
__global__ __launch_bounds__(256) void gemm512_k(
    const float* __restrict__ X, const float* __restrict__ W,
    float* __restrict__ Y, const float* __restrict__ bias,
    const float* __restrict__ resid)
{
  __shared__ float As[16][68];   // [k][m], +4 pad keeps 16B align & breaks conflicts
  __shared__ float Bs[16][64];   // [k][n]
  const int bm = blockIdx.x * 64;
  const int bn = blockIdx.y * 64;
  const int t  = threadIdx.x;
  const int tx = t & 15;   // n-group (4 cols each)
  const int ty = t >> 4;   // m-group (4 rows each)

  float acc[4][4];
#pragma unroll
  for (int i = 0; i < 4; ++i)
#pragma unroll
    for (int j = 0; j < 4; ++j) acc[i][j] = 0.f;

  for (int k0 = 0; k0 < 512; k0 += 16) {
    // stage A tile 64x16 -> As[k][m]
#pragma unroll
    for (int mp = 0; mp < 4; ++mp) {
      const int m = ty + 16 * mp;
      As[tx][m] = X[(size_t)(bm + m) * 512 + k0 + tx];
    }
    // stage B tile 16x64 -> Bs[k][n]
    const int nn = t & 63;
#pragma unroll
    for (int kp = 0; kp < 4; ++kp) {
      const int kk = (t >> 6) + 4 * kp;
      Bs[kk][nn] = W[(size_t)(k0 + kk) * 512 + bn + nn];
    }
    __syncthreads();
#pragma unroll
    for (int k = 0; k < 16; ++k) {
      const float4 a = *reinterpret_cast<const float4*>(&As[k][ty * 4]);
      const float4 b = *reinterpret_cast<const float4*>(&Bs[k][tx * 4]);
      const float av[4] = {a.x, a.y, a.z, a.w};
      const float bv[4] = {b.x, b.y, b.z, b.w};
#pragma unroll
      for (int i = 0; i < 4; ++i)
#pragma unroll
        for (int j = 0; j < 4; ++j) acc[i][j] += av[i] * bv[j];
    }
    __syncthreads();
  }

#pragma unroll
  for (int i = 0; i < 4; ++i) {
    const int m = bm + ty * 4 + i;
    const int n = bn + tx * 4;
    float4 o = make_float4(acc[i][0], acc[i][1], acc[i][2], acc[i][3]);
    if (bias) {
      const float4 bb = *reinterpret_cast<const float4*>(&bias[n]);
      const float4 rr = *reinterpret_cast<const float4*>(&resid[(size_t)m * 512 + n]);
      o.x += bb.x + rr.x; o.y += bb.y + rr.y;
      o.z += bb.z + rr.z; o.w += bb.w + rr.w;
    }
    *reinterpret_cast<float4*>(&Y[(size_t)m * 512 + n]) = o;
  }
}

// ---------------------------------------------------------------------------
// Sparse gather attention with RPE. One block per (b, s). 256 threads.
// Phase 1: q row + indices -> LDS.
// Phase 2: thread t -> (h = t>>5, n = t&31): score = q_h . k[idx[n]]_h + rpe;
//          softmax over n within 32-lane shuffle groups.
// Phase 3: thread t -> ctx elements t and t+256, sum over 32 gathered V rows.
// ---------------------------------------------------------------------------
__global__ __launch_bounds__(256) void attn_k(
    const float* __restrict__ qb, const float* __restrict__ kb,
    const float* __restrict__ vb, const float* __restrict__ rpe,
    const int* __restrict__ qkm, float* __restrict__ ctx)
{
  __shared__ float qs[512];
  __shared__ float attn_s[8][32];
  __shared__ int   idx_s[32];

  const int bs = blockIdx.x;          // b*S + s
  const int b  = bs >> 11;            // / 2048
  const int s  = bs & 2047;
  const int t  = threadIdx.x;

  qs[t]       = qb[(size_t)bs * 512 + t];
  qs[t + 256] = qb[(size_t)bs * 512 + t + 256];
  if (t < NKk) idx_s[t] = qkm[s * NKk + t];
  __syncthreads();

  // ---- scores + softmax ----
  const int h = t >> 5;   // 0..7
  const int n = t & 31;
  const int im = idx_s[n];
  const bool valid = (im >= 0);
  const int kr = valid ? im : 0;

  const float4* krow = reinterpret_cast<const float4*>(kb + ((size_t)b * Ss + kr) * 512 + h * 64);
  const float4* qrow = reinterpret_cast<const float4*>(qs + h * 64);
  float sc = 0.f;
#pragma unroll
  for (int d4 = 0; d4 < 16; ++d4) {
    const float4 kk = krow[d4];
    const float4 qq = qrow[d4];
    sc += qq.x * kk.x + qq.y * kk.y + qq.z * kk.z + qq.w * kk.w;
  }
  sc += rpe[((size_t)bs * NKk + n) * Hh + h];
  sc = valid ? sc * 0.125f : -1e30f;   // (qk+rpe)/sqrt(64); invalid -> -inf-ish

  float mx = sc;
#pragma unroll
  for (int m = 16; m >= 1; m >>= 1) mx = fmaxf(mx, __shfl_xor(mx, m, 32));
  const float p = valid ? __expf(sc - mx) : 0.f;
  float sum = p;
#pragma unroll
  for (int m = 16; m >= 1; m >>= 1) sum += __shfl_xor(sum, m, 32);
  attn_s[h][n] = (sum > 0.f) ? (p / sum) : 0.f;
  __syncthreads();

  // ---- ctx = attn @ gathered V ----
  const int h0 = t >> 6;   // 0..3 (wave-uniform)
  const int d0 = t & 63;
  float c0 = 0.f, c1 = 0.f;
  for (int n2 = 0; n2 < 32; ++n2) {
    int row = idx_s[n2];
    row = row < 0 ? 0 : row;            // attn weight is 0 for invalid
    const float* vrow = vb + ((size_t)b * Ss + row) * 512;
    c0 += attn_s[h0][n2]     * vrow[h0 * 64 + d0];
    c1 += attn_s[h0 + 4][n2] * vrow[(h0 + 4) * 64 + d0];
  }
  ctx[(size_t)bs * 512 + t]       = c0;
  ctx[(size_t)bs * 512 + t + 256] = c1;
}

// ---------------------------------------------------------------------------
// In-place row LayerNorm over DM=512. One wave per row, 4 rows per block.
// ---------------------------------------------------------------------------
__global__ __launch_bounds__(256) void ln_k(
    float* __restrict__ x, const float* __restrict__ g,
    const float* __restrict__ bta)
{
  const int w    = threadIdx.x >> 6;
  const int lane = threadIdx.x & 63;
  const int row  = blockIdx.x * 4 + w;

  float4* xr = reinterpret_cast<float4*>(x + (size_t)row * 512);
  const float4 v0 = xr[lane];
  const float4 v1 = xr[lane + 64];

  float sum = v0.x + v0.y + v0.z + v0.w + v1.x + v1.y + v1.z + v1.w;
  float sq  = v0.x * v0.x + v0.y * v0.y + v0.z * v0.z + v0.w * v0.w
            + v1.x * v1.x + v1.y * v1.y + v1.z * v1.z + v1.w * v1.w;
#pragma unroll
  for (int m = 32; m >= 1; m >>= 1) {
    sum += __shfl_xor(sum, m, 64);
    sq  += __shfl_xor(sq,  m, 64);
  }
  const float mu  = sum * (1.f / 512.f);
  const float var = sq * (1.f / 512.f) - mu * mu;
  const float rs  = rsqrtf(var + 1e-6f);

  const float4 g0 = reinterpret_cast<const float4*>(g)[lane];
  const float4 g1 = reinterpret_cast<const float4*>(g)[lane + 64];
  const float4 b0 = reinterpret_cast<const float4*>(bta)[lane];
  const float4 b1 = reinterpret_cast<const float4*>(bta)[lane + 64];

  float4 o0, o1;
  o0.x = (v0.x - mu) * rs * g0.x + b0.x;
  o0.y = (v0.y - mu) * rs * g0.y + b0.y;
  o0.z = (v0.z - mu) * rs * g0.z + b0.z;
  o0.w = (v0.w - mu) * rs * g0.w + b0.w;
  o1.x = (v1.x - mu) * rs * g1.x + b1.x;
  o1.y = (v1.y - mu) * rs * g1.y + b1.y;
  o1.z = (v1.z - mu) * rs * g1.z + b1.z;
  o1.w = (v1.w - mu) * rs * g1.w + b1.w;
  xr[lane]      = o0;
  xr[lane + 64] = o1;
}

extern "C" void kernel_launch(void* const* d_in, const int* in_sizes, int n_in,
                              void* d_out, int out_size, void* d_ws, size_t ws_size,
                              hipStream_t stream) {
  const float* hs  = (const float*)d_in[0];   // (B,S,DM)
  const float* rpe = (const float*)d_in[1];   // (B,S,NK,H)
  const int*   qkm = (const int*)d_in[2];     // (S,NK)
  // d_in[3] = k_q_mask (unused by reference)
  const float* wq  = (const float*)d_in[4];   // (DM, H*D)
  const float* wk  = (const float*)d_in[5];
  const float* wv  = (const float*)d_in[6];
  const float* fcw = (const float*)d_in[7];   // (H*D, DM)
  const float* fcb = (const float*)d_in[8];   // (DM,)
  const float* lng = (const float*)d_in[9];
  const float* lnb = (const float*)d_in[10];
  float* out = (float*)d_out;

  float* q  = (float*)d_ws;                   // 4 buffers x 8.4 MB = 33.6 MB
  float* k  = q + (size_t)Mm * DMm;
  float* v  = k + (size_t)Mm * DMm;
  float* cx = v + (size_t)Mm * DMm;

  const dim3 gg(Mm / 64, DMm / 64);
  gemm512_k<<<gg, 256, 0, stream>>>(hs, wq, q, nullptr, nullptr);
  gemm512_k<<<gg, 256, 0, stream>>>(hs, wk, k, nullptr, nullptr);
  gemm512_k<<<gg, 256, 0, stream>>>(hs, wv, v, nullptr, nullptr);
  attn_k<<<Mm, 256, 0, stream>>>(q, k, v, rpe, qkm, cx);
  // fc + bias + residual, written straight into d_out (pre-LN)
  gemm512_k<<<gg, 256, 0, stream>>>(cx, fcw, out, fcb, hs);
  // in-place LayerNorm on d_out
  ln_k<<<Mm / 4, 256, 0, stream>>>(out, lng, lnb);
}

// Round 2
// 90.514 us; speedup vs baseline: 2.3254x; 2.3254x over previous
//
#include <hip/hip_runtime.h>
#include <hip/hip_bf16.h>

// (B, S, NK, H, D, DM) = (2, 2048, 32, 8, 64, 512)
constexpr int Bb  = 2;
constexpr int Ss  = 2048;
constexpr int NKk = 32;
constexpr int Hh  = 8;
constexpr int DMm = 512;
constexpr int Mm  = Bb * Ss;   // 4096 rows

typedef __attribute__((ext_vector_type(8))) short bf16x8;
typedef __attribute__((ext_vector_type(4))) float f32x4;

__device__ __forceinline__ float b2f(unsigned short u) {
  return __uint_as_float((unsigned)u << 16);
}
__device__ __forceinline__ unsigned short f2b(float f) {
  unsigned u = __float_as_uint(f);
  unsigned r = (u + 0x7fffu + ((u >> 16) & 1u)) >> 16;   // RNE
  return (unsigned short)r;
}

// ---------------------------------------------------------------------------
// fp32 -> bf16 (flat), 8 elems/thread
// ---------------------------------------------------------------------------
__global__ __launch_bounds__(256) void cvt_bf16_k(
    const float* __restrict__ x, ushort* __restrict__ y, int n8)
{
  const int i = blockIdx.x * 256 + threadIdx.x;
  if (i >= n8) return;
  const float4 a = reinterpret_cast<const float4*>(x)[2 * i];
  const float4 b = reinterpret_cast<const float4*>(x)[2 * i + 1];
  ushort o[8] = {f2b(a.x), f2b(a.y), f2b(a.z), f2b(a.w),
                 f2b(b.x), f2b(b.y), f2b(b.z), f2b(b.w)};
  reinterpret_cast<uint4*>(y)[i] = *reinterpret_cast<uint4*>(o);
}

// ---------------------------------------------------------------------------
// Weight transpose+convert: W fp32 [k][n] (512x512) -> Wt bf16 [n][k]
// 64x64 tile per block, 256 threads.
// ---------------------------------------------------------------------------
__global__ __launch_bounds__(256) void cvt_wt_k(
    const float* __restrict__ W, ushort* __restrict__ Wt)
{
  __shared__ float tile[64][65];
  const int k0 = blockIdx.x * 64, n0 = blockIdx.y * 64;
  const int t = threadIdx.x;
#pragma unroll
  for (int p = 0; p < 4; ++p) {
    const int r = (t >> 4) + p * 16, c = (t & 15) * 4;
    const float4 v = *reinterpret_cast<const float4*>(&W[(size_t)(k0 + r) * 512 + n0 + c]);
    tile[r][c] = v.x; tile[r][c + 1] = v.y; tile[r][c + 2] = v.z; tile[r][c + 3] = v.w;
  }
  __syncthreads();
  const int n = t >> 2, ks = (t & 3) * 16;
  ushort o[16];
#pragma unroll
  for (int i = 0; i < 16; ++i) o[i] = f2b(tile[ks + i][n]);
  *reinterpret_cast<uint4*>(&Wt[(size_t)(n0 + n) * 512 + k0 + ks])     = *reinterpret_cast<uint4*>(&o[0]);
  *reinterpret_cast<uint4*>(&Wt[(size_t)(n0 + n) * 512 + k0 + ks + 8]) = *reinterpret_cast<uint4*>(&o[8]);
}

// ---------------------------------------------------------------------------
// bf16 MFMA GEMM: Y = Xb @ Wt^T   (Xb: [M][512] bf16, Wt: [n][k] bf16)
// BM=128, BN=64, BK=64. 4 waves (2x2), per-wave 64x32 = 4x2 16x16 frags.
// OUT_BF16=1: Y bf16 [m][n] via LDS-repacked coalesced stores.
// OUT_BF16=0: Y fp32 + bias[n] + resid[m][n] (fc epilogue).
// Frag layouts (mfma_f32_16x16x32_bf16):
//   A: lane holds A[row=lane&15][k=(lane>>4)*8 + i], i=0..7  (k-contiguous)
//   B: lane holds B[k=(lane>>4)*8 + i][col=lane&15]          (k-contiguous)
//   D: lane reg r -> D[row=(lane>>4)*4+r][col=lane&15]   [m89-verified]
// ---------------------------------------------------------------------------
template <int OUT_BF16>
__global__ __launch_bounds__(256) void gemm_mfma(
    const ushort* __restrict__ Xb, const ushort* __restrict__ Wt,
    void* __restrict__ Yv, const float* __restrict__ bias,
    const float* __restrict__ resid)
{
  __shared__ ushort As[128][72];   // +8 bf16 pad: row stride 144B -> 2-way max
  __shared__ ushort Bs[64][72];
  const int bm = blockIdx.x * 128;
  const int bn = blockIdx.y * 64;
  const int t = threadIdx.x;
  const int wave = t >> 6, lane = t & 63;
  const int wm = (wave >> 1) * 64;   // 0 / 64
  const int wn = (wave & 1) * 32;    // 0 / 32

  f32x4 acc[4][2] = {};

  for (int k0 = 0; k0 < 512; k0 += 64) {
#pragma unroll
    for (int p = 0; p < 4; ++p) {                 // A: 128x64 bf16 = 16 KB
      const int i = p * 256 + t;
      const int row = i >> 3, kc = (i & 7) * 8;
      *reinterpret_cast<uint4*>(&As[row][kc]) =
          *reinterpret_cast<const uint4*>(&Xb[(size_t)(bm + row) * 512 + k0 + kc]);
    }
#pragma unroll
    for (int p = 0; p < 2; ++p) {                 // B: 64x64 bf16 = 8 KB
      const int i = p * 256 + t;
      const int row = i >> 3, kc = (i & 7) * 8;
      *reinterpret_cast<uint4*>(&Bs[row][kc]) =
          *reinterpret_cast<const uint4*>(&Wt[(size_t)(bn + row) * 512 + k0 + kc]);
    }
    __syncthreads();
#pragma unroll
    for (int ks = 0; ks < 2; ++ks) {
      const int kk = ks * 32 + (lane >> 4) * 8;
      bf16x8 af[4], bfr[2];
#pragma unroll
      for (int i = 0; i < 4; ++i)
        af[i] = *reinterpret_cast<const bf16x8*>(&As[wm + i * 16 + (lane & 15)][kk]);
#pragma unroll
      for (int j = 0; j < 2; ++j)
        bfr[j] = *reinterpret_cast<const bf16x8*>(&Bs[wn + j * 16 + (lane & 15)][kk]);
#pragma unroll
      for (int i = 0; i < 4; ++i)
#pragma unroll
        for (int j = 0; j < 2; ++j)
          acc[i][j] = __builtin_amdgcn_mfma_f32_16x16x32_bf16(af[i], bfr[j], acc[i][j], 0, 0, 0);
    }
    __syncthreads();
  }

  if (OUT_BF16) {
    // repack 128x64 bf16 tile through As, then coalesced uint4 stores
#pragma unroll
    for (int i = 0; i < 4; ++i)
#pragma unroll
      for (int j = 0; j < 2; ++j)
#pragma unroll
        for (int r = 0; r < 4; ++r)
          As[wm + i * 16 + (lane >> 4) * 4 + r][wn + j * 16 + (lane & 15)] = f2b(acc[i][j][r]);
    __syncthreads();
    ushort* Y = reinterpret_cast<ushort*>(Yv);
#pragma unroll
    for (int p = 0; p < 4; ++p) {
      const int i = p * 256 + t;
      const int row = i >> 3, kc = (i & 7) * 8;
      *reinterpret_cast<uint4*>(&Y[(size_t)(bm + row) * 512 + bn + kc]) =
          *reinterpret_cast<uint4*>(&As[row][kc]);
    }
  } else {
    float* Y = reinterpret_cast<float*>(Yv);
#pragma unroll
    for (int i = 0; i < 4; ++i) {
#pragma unroll
      for (int j = 0; j < 2; ++j) {
        const int m = bm + wm + i * 16 + (lane >> 4) * 4;
        const int n = bn + wn + j * 16 + (lane & 15);
        const float bb = bias[n];
#pragma unroll
        for (int r = 0; r < 4; ++r)
          Y[(size_t)(m + r) * 512 + n] = acc[i][j][r] + bb + resid[(size_t)(m + r) * 512 + n];
      }
    }
  }
}

// ---------------------------------------------------------------------------
// Sparse gather attention, bf16 K/V/Q. One block per (b,s), 256 threads.
// ---------------------------------------------------------------------------
__global__ __launch_bounds__(256) void attn_k2(
    const ushort* __restrict__ qb, const ushort* __restrict__ kb,
    const ushort* __restrict__ vb, const float* __restrict__ rpe,
    const int* __restrict__ qkm, ushort* __restrict__ ctx)
{
  __shared__ float qs[512];
  __shared__ float attn_s[8][33];
  __shared__ int   idx_s[32];

  const int bs = blockIdx.x;
  const int b  = bs >> 11;
  const int s  = bs & 2047;
  const int t  = threadIdx.x;

  qs[t]       = b2f(qb[(size_t)bs * 512 + t]);
  qs[t + 256] = b2f(qb[(size_t)bs * 512 + t + 256]);
  if (t < NKk) idx_s[t] = qkm[s * NKk + t];
  __syncthreads();

  // ---- scores + softmax (thread = (h, n)) ----
  const int h = t >> 5, n = t & 31;
  const int im = idx_s[n];
  const bool valid = (im >= 0);
  const int kr = valid ? im : 0;

  const uint4* krow = reinterpret_cast<const uint4*>(kb + ((size_t)b * Ss + kr) * 512 + h * 64);
  float sc = 0.f;
#pragma unroll
  for (int c = 0; c < 8; ++c) {
    const uint4 kk = krow[c];
    const float* qq = &qs[h * 64 + c * 8];
    sc += qq[0] * __uint_as_float(kk.x << 16) + qq[1] * __uint_as_float(kk.x & 0xffff0000u)
        + qq[2] * __uint_as_float(kk.y << 16) + qq[3] * __uint_as_float(kk.y & 0xffff0000u)
        + qq[4] * __uint_as_float(kk.z << 16) + qq[5] * __uint_as_float(kk.z & 0xffff0000u)
        + qq[6] * __uint_as_float(kk.w << 16) + qq[7] * __uint_as_float(kk.w & 0xffff0000u);
  }
  sc += rpe[((size_t)bs * NKk + n) * Hh + h];
  sc = valid ? sc * 0.125f : -1e30f;

  float mx = sc;
#pragma unroll
  for (int m = 16; m >= 1; m >>= 1) mx = fmaxf(mx, __shfl_xor(mx, m, 32));
  const float p = valid ? __expf(sc - mx) : 0.f;
  float sum = p;
#pragma unroll
  for (int m = 16; m >= 1; m >>= 1) sum += __shfl_xor(sum, m, 32);
  attn_s[h][n] = (sum > 0.f) ? (p / sum) : 0.f;
  __syncthreads();

  // ---- ctx = attn @ gathered V (thread = (h0, d0), two heads each) ----
  const int h0 = t >> 6;   // 0..3 wave-uniform
  const int d0 = t & 63;
  float c0 = 0.f, c1 = 0.f;
  for (int n2 = 0; n2 < 32; ++n2) {
    int row = idx_s[n2];
    row = row < 0 ? 0 : row;
    const ushort* vrow = vb + ((size_t)b * Ss + row) * 512;
    c0 += attn_s[h0][n2]     * b2f(vrow[h0 * 64 + d0]);
    c1 += attn_s[h0 + 4][n2] * b2f(vrow[(h0 + 4) * 64 + d0]);
  }
  ctx[(size_t)bs * 512 + t]       = f2b(c0);
  ctx[(size_t)bs * 512 + t + 256] = f2b(c1);
}

// ---------------------------------------------------------------------------
// In-place row LayerNorm over DM=512. One wave per row, 4 rows per block.
// ---------------------------------------------------------------------------
__global__ __launch_bounds__(256) void ln_k(
    float* __restrict__ x, const float* __restrict__ g,
    const float* __restrict__ bta)
{
  const int w    = threadIdx.x >> 6;
  const int lane = threadIdx.x & 63;
  const int row  = blockIdx.x * 4 + w;

  float4* xr = reinterpret_cast<float4*>(x + (size_t)row * 512);
  const float4 v0 = xr[lane];
  const float4 v1 = xr[lane + 64];

  float sum = v0.x + v0.y + v0.z + v0.w + v1.x + v1.y + v1.z + v1.w;
  float sq  = v0.x * v0.x + v0.y * v0.y + v0.z * v0.z + v0.w * v0.w
            + v1.x * v1.x + v1.y * v1.y + v1.z * v1.z + v1.w * v1.w;
#pragma unroll
  for (int m = 32; m >= 1; m >>= 1) {
    sum += __shfl_xor(sum, m, 64);
    sq  += __shfl_xor(sq,  m, 64);
  }
  const float mu  = sum * (1.f / 512.f);
  const float var = sq * (1.f / 512.f) - mu * mu;
  const float rs  = rsqrtf(var + 1e-6f);

  const float4 g0 = reinterpret_cast<const float4*>(g)[lane];
  const float4 g1 = reinterpret_cast<const float4*>(g)[lane + 64];
  const float4 b0 = reinterpret_cast<const float4*>(bta)[lane];
  const float4 b1 = reinterpret_cast<const float4*>(bta)[lane + 64];

  float4 o0, o1;
  o0.x = (v0.x - mu) * rs * g0.x + b0.x;
  o0.y = (v0.y - mu) * rs * g0.y + b0.y;
  o0.z = (v0.z - mu) * rs * g0.z + b0.z;
  o0.w = (v0.w - mu) * rs * g0.w + b0.w;
  o1.x = (v1.x - mu) * rs * g1.x + b1.x;
  o1.y = (v1.y - mu) * rs * g1.y + b1.y;
  o1.z = (v1.z - mu) * rs * g1.z + b1.z;
  o1.w = (v1.w - mu) * rs * g1.w + b1.w;
  xr[lane]      = o0;
  xr[lane + 64] = o1;
}

extern "C" void kernel_launch(void* const* d_in, const int* in_sizes, int n_in,
                              void* d_out, int out_size, void* d_ws, size_t ws_size,
                              hipStream_t stream) {
  const float* hs  = (const float*)d_in[0];
  const float* rpe = (const float*)d_in[1];
  const int*   qkm = (const int*)d_in[2];
  const float* wq  = (const float*)d_in[4];
  const float* wk  = (const float*)d_in[5];
  const float* wv  = (const float*)d_in[6];
  const float* fcw = (const float*)d_in[7];
  const float* fcb = (const float*)d_in[8];
  const float* lng = (const float*)d_in[9];
  const float* lnb = (const float*)d_in[10];
  float* out = (float*)d_out;

  // workspace layout (all bf16 / ushort)
  ushort* Xb  = (ushort*)d_ws;                       // 4096*512
  ushort* Wtq = Xb  + (size_t)Mm * DMm;              // 512*512 each
  ushort* Wtk = Wtq + (size_t)DMm * DMm;
  ushort* Wtv = Wtk + (size_t)DMm * DMm;
  ushort* Wtf = Wtv + (size_t)DMm * DMm;
  ushort* qb  = Wtf + (size_t)DMm * DMm;             // 4096*512 each
  ushort* kb  = qb  + (size_t)Mm * DMm;
  ushort* vb  = kb  + (size_t)Mm * DMm;
  ushort* cxb = vb  + (size_t)Mm * DMm;

  cvt_bf16_k<<<(Mm * DMm / 8 + 255) / 256, 256, 0, stream>>>(hs, Xb, Mm * DMm / 8);
  const dim3 gt(8, 8);
  cvt_wt_k<<<gt, 256, 0, stream>>>(wq,  Wtq);
  cvt_wt_k<<<gt, 256, 0, stream>>>(wk,  Wtk);
  cvt_wt_k<<<gt, 256, 0, stream>>>(wv,  Wtv);
  cvt_wt_k<<<gt, 256, 0, stream>>>(fcw, Wtf);

  const dim3 gg(Mm / 128, DMm / 64);
  gemm_mfma<1><<<gg, 256, 0, stream>>>(Xb, Wtq, qb, nullptr, nullptr);
  gemm_mfma<1><<<gg, 256, 0, stream>>>(Xb, Wtk, kb, nullptr, nullptr);
  gemm_mfma<1><<<gg, 256, 0, stream>>>(Xb, Wtv, vb, nullptr, nullptr);

  attn_k2<<<Mm, 256, 0, stream>>>(qb, kb, vb, rpe, qkm, cxb);

  gemm_mfma<0><<<gg, 256, 0, stream>>>(cxb, Wtf, out, fcb, hs);
  ln_k<<<Mm / 4, 256, 0, stream>>>(out, lng, lnb);
}

// Round 3
// 64.437 us; speedup vs baseline: 3.2664x; 1.4047x over previous
//
#include <hip/hip_runtime.h>
#include <hip/hip_bf16.h>

// (B, S, NK, H, D, DM) = (2, 2048, 32, 8, 64, 512)
constexpr int Bb  = 2;
constexpr int Ss  = 2048;
constexpr int NKk = 32;
constexpr int Hh  = 8;
constexpr int DMm = 512;
constexpr int Mm  = Bb * Ss;   // 4096 rows
constexpr int QKV = 1536;      // concat row stride

typedef __attribute__((ext_vector_type(8))) short bf16x8;
typedef __attribute__((ext_vector_type(4))) float f32x4;

__device__ __forceinline__ float b2f(unsigned short u) {
  return __uint_as_float((unsigned)u << 16);
}
__device__ __forceinline__ unsigned short f2b(float f) {
  unsigned u = __float_as_uint(f);
  unsigned r = (u + 0x7fffu + ((u >> 16) & 1u)) >> 16;   // RNE
  return (unsigned short)r;
}
__device__ __forceinline__ void gload_lds16(const ushort* g, ushort* l) {
  __builtin_amdgcn_global_load_lds(
      (const __attribute__((address_space(1))) void*)g,
      (__attribute__((address_space(3))) void*)l, 16, 0, 0);
}

// ---------------------------------------------------------------------------
// fp32 -> bf16 (flat), 8 elems/thread
// ---------------------------------------------------------------------------
__global__ __launch_bounds__(256) void cvt_bf16_k(
    const float* __restrict__ x, ushort* __restrict__ y, int n8)
{
  const int i = blockIdx.x * 256 + threadIdx.x;
  if (i >= n8) return;
  const float4 a = reinterpret_cast<const float4*>(x)[2 * i];
  const float4 b = reinterpret_cast<const float4*>(x)[2 * i + 1];
  ushort o[8] = {f2b(a.x), f2b(a.y), f2b(a.z), f2b(a.w),
                 f2b(b.x), f2b(b.y), f2b(b.z), f2b(b.w)};
  reinterpret_cast<uint4*>(y)[i] = *reinterpret_cast<uint4*>(o);
}

// ---------------------------------------------------------------------------
// Weight transpose+convert, all 4 weights in one launch (z = which weight).
// W fp32 [k][n] (512x512) -> Wt bf16 [n][k]; q/k/v go into Wt3 rows
// {0..511, 512..1023, 1024..1535}, fc into Wtf.
// ---------------------------------------------------------------------------
__global__ __launch_bounds__(256) void cvt_wt_k(
    const float* __restrict__ Wq, const float* __restrict__ Wk,
    const float* __restrict__ Wv, const float* __restrict__ Wf,
    ushort* __restrict__ Wt3, ushort* __restrict__ Wtf)
{
  __shared__ float tile[64][65];
  const int z = blockIdx.z;
  const float* W = (z == 0) ? Wq : (z == 1) ? Wk : (z == 2) ? Wv : Wf;
  ushort* Wt = (z < 3) ? (Wt3 + (size_t)z * 512 * 512) : Wtf;

  const int k0 = blockIdx.x * 64, n0 = blockIdx.y * 64;
  const int t = threadIdx.x;
#pragma unroll
  for (int p = 0; p < 4; ++p) {
    const int r = (t >> 4) + p * 16, c = (t & 15) * 4;
    const float4 v = *reinterpret_cast<const float4*>(&W[(size_t)(k0 + r) * 512 + n0 + c]);
    tile[r][c] = v.x; tile[r][c + 1] = v.y; tile[r][c + 2] = v.z; tile[r][c + 3] = v.w;
  }
  __syncthreads();
  const int n = t >> 2, ks = (t & 3) * 16;
  ushort o[16];
#pragma unroll
  for (int i = 0; i < 16; ++i) o[i] = f2b(tile[ks + i][n]);
  *reinterpret_cast<uint4*>(&Wt[(size_t)(n0 + n) * 512 + k0 + ks])     = *reinterpret_cast<uint4*>(&o[0]);
  *reinterpret_cast<uint4*>(&Wt[(size_t)(n0 + n) * 512 + k0 + ks + 8]) = *reinterpret_cast<uint4*>(&o[8]);
}

// ---------------------------------------------------------------------------
// bf16 MFMA GEMM: Y = Xb @ Wt^T   (Xb: [M][512] bf16, Wt: [n][k] bf16)
// BM=128, BN=64, BK=64. 4 waves (2x2), per-wave 64x32 = 4x2 16x16 frags.
// OUT_BF16=1: Y bf16 (row stride ldY) via LDS-repacked coalesced stores.
// OUT_BF16=0: Y fp32 + bias[n] + resid[m][n].
// ---------------------------------------------------------------------------
template <int OUT_BF16>
__global__ __launch_bounds__(256) void gemm_mfma(
    const ushort* __restrict__ Xb, const ushort* __restrict__ Wt,
    void* __restrict__ Yv, const float* __restrict__ bias,
    const float* __restrict__ resid, int ldY)
{
  __shared__ ushort As[128][72];
  __shared__ ushort Bs[64][72];
  const int bm = blockIdx.x * 128;
  const int bn = blockIdx.y * 64;
  const int t = threadIdx.x;
  const int wave = t >> 6, lane = t & 63;
  const int wm = (wave >> 1) * 64;
  const int wn = (wave & 1) * 32;

  f32x4 acc[4][2] = {};

  for (int k0 = 0; k0 < 512; k0 += 64) {
#pragma unroll
    for (int p = 0; p < 4; ++p) {
      const int i = p * 256 + t;
      const int row = i >> 3, kc = (i & 7) * 8;
      *reinterpret_cast<uint4*>(&As[row][kc]) =
          *reinterpret_cast<const uint4*>(&Xb[(size_t)(bm + row) * 512 + k0 + kc]);
    }
#pragma unroll
    for (int p = 0; p < 2; ++p) {
      const int i = p * 256 + t;
      const int row = i >> 3, kc = (i & 7) * 8;
      *reinterpret_cast<uint4*>(&Bs[row][kc]) =
          *reinterpret_cast<const uint4*>(&Wt[(size_t)(bn + row) * 512 + k0 + kc]);
    }
    __syncthreads();
#pragma unroll
    for (int ks = 0; ks < 2; ++ks) {
      const int kk = ks * 32 + (lane >> 4) * 8;
      bf16x8 af[4], bfr[2];
#pragma unroll
      for (int i = 0; i < 4; ++i)
        af[i] = *reinterpret_cast<const bf16x8*>(&As[wm + i * 16 + (lane & 15)][kk]);
#pragma unroll
      for (int j = 0; j < 2; ++j)
        bfr[j] = *reinterpret_cast<const bf16x8*>(&Bs[wn + j * 16 + (lane & 15)][kk]);
#pragma unroll
      for (int i = 0; i < 4; ++i)
#pragma unroll
        for (int j = 0; j < 2; ++j)
          acc[i][j] = __builtin_amdgcn_mfma_f32_16x16x32_bf16(af[i], bfr[j], acc[i][j], 0, 0, 0);
    }
    __syncthreads();
  }

  if (OUT_BF16) {
#pragma unroll
    for (int i = 0; i < 4; ++i)
#pragma unroll
      for (int j = 0; j < 2; ++j)
#pragma unroll
        for (int r = 0; r < 4; ++r)
          As[wm + i * 16 + (lane >> 4) * 4 + r][wn + j * 16 + (lane & 15)] = f2b(acc[i][j][r]);
    __syncthreads();
    ushort* Y = reinterpret_cast<ushort*>(Yv);
#pragma unroll
    for (int p = 0; p < 4; ++p) {
      const int i = p * 256 + t;
      const int row = i >> 3, kc = (i & 7) * 8;
      *reinterpret_cast<uint4*>(&Y[(size_t)(bm + row) * ldY + bn + kc]) =
          *reinterpret_cast<uint4*>(&As[row][kc]);
    }
  } else {
    float* Y = reinterpret_cast<float*>(Yv);
#pragma unroll
    for (int i = 0; i < 4; ++i) {
#pragma unroll
      for (int j = 0; j < 2; ++j) {
        const int m = bm + wm + i * 16 + (lane >> 4) * 4;
        const int n = bn + wn + j * 16 + (lane & 15);
        const float bb = bias[n];
#pragma unroll
        for (int r = 0; r < 4; ++r)
          Y[(size_t)(m + r) * ldY + n] = acc[i][j][r] + bb + resid[(size_t)(m + r) * 512 + n];
      }
    }
  }
}

// ---------------------------------------------------------------------------
// Sparse gather attention. One block per (b,s), 256 threads (4 waves).
// qkv layout: [b*S+s][1536] = q(0..511) | k(512..1023) | v(1024..1535), bf16.
// Phase 1: q -> qs (fp32); 32 gathered K rows -> Ks via global_load_lds,
//          16B-block XOR-swizzled through the SOURCE address (slot l holds
//          global block l ^ (n&7)).  ONE barrier total.
// Phase 2: thread t = (h = t>>5, n = t&31): dot from LDS (b128 reads at the
//          8-pass structural minimum), + rpe, mask, 32-lane shfl softmax.
//          Normalized weight stays in register pn.
// Phase 3: thread t -> ctx elems 2t, 2t+1 (same h = t>>5 as phase 2).
//          attn weight and gather index fetched by __shfl from the same wave.
// ---------------------------------------------------------------------------
__global__ __launch_bounds__(256) void attn_k3(
    const ushort* __restrict__ qkv, const float* __restrict__ rpe,
    const int* __restrict__ qkm, ushort* __restrict__ ctx)
{
  __shared__ ushort Ks[32 * 512];   // row n at n*512, block-swizzled
  __shared__ float  qs[512];

  const int bs = blockIdx.x;
  const int b  = bs >> 11;
  const int s  = bs & 2047;
  const int t  = threadIdx.x;
  const int wv = t >> 6, lane = t & 63;

  // ---- phase 1: q -> LDS (fp32), K rows -> LDS (async, swizzled source) ----
  const ushort* qrow = qkv + (size_t)bs * QKV;
  qs[t]       = b2f(qrow[t]);
  qs[t + 256] = b2f(qrow[t + 256]);

#pragma unroll
  for (int r = 0; r < 8; ++r) {
    const int n = r * 4 + wv;                 // wave-uniform row
    int im = qkm[s * NKk + n];                // same addr across wave
    im = im < 0 ? 0 : im;
    const ushort* gsrc = qkv + (size_t)(b * Ss + im) * QKV + 512
                       + ((lane ^ (n & 7)) * 8);
    gload_lds16(gsrc, &Ks[n * 512]);          // lane l -> Ks[n*512 + l*8]
  }

  // per-thread gather index (for phase 3 shfl) — n = lane&31
  int iv = qkm[s * NKk + (lane & 31)];

  __syncthreads();   // drains vmcnt (global_load_lds) + lgkmcnt

  // ---- phase 2: scores + softmax ----
  const int h = t >> 5;        // 0..7  (wave w holds h = 2w, 2w+1)
  const int n = t & 31;
  const bool valid = (iv >= 0);   // iv for this thread IS index n

  float2 a2 = make_float2(0.f, 0.f);
#pragma unroll
  for (int j = 0; j < 8; ++j) {
    const int blk = (h * 8 + j) ^ (n & 7);
    const uint4 kk = *reinterpret_cast<const uint4*>(&Ks[n * 512 + blk * 8]);
    const float* qq = &qs[h * 64 + j * 8];
    a2.x += qq[0] * __uint_as_float(kk.x << 16);
    a2.y += qq[1] * __uint_as_float(kk.x & 0xffff0000u);
    a2.x += qq[2] * __uint_as_float(kk.y << 16);
    a2.y += qq[3] * __uint_as_float(kk.y & 0xffff0000u);
    a2.x += qq[4] * __uint_as_float(kk.z << 16);
    a2.y += qq[5] * __uint_as_float(kk.z & 0xffff0000u);
    a2.x += qq[6] * __uint_as_float(kk.w << 16);
    a2.y += qq[7] * __uint_as_float(kk.w & 0xffff0000u);
  }
  float sc = a2.x + a2.y + rpe[((size_t)bs * NKk + n) * Hh + h];
  sc = valid ? sc * 0.125f : -1e30f;

  float mx = sc;
#pragma unroll
  for (int m = 16; m >= 1; m >>= 1) mx = fmaxf(mx, __shfl_xor(mx, m, 32));
  const float p = valid ? __expf(sc - mx) : 0.f;
  float sum = p;
#pragma unroll
  for (int m = 16; m >= 1; m >>= 1) sum += __shfl_xor(sum, m, 32);
  const float pn = (sum > 0.f) ? (p / sum) : 0.f;

  // ---- phase 3: ctx elems 2t, 2t+1 (h = t>>5 matches phase 2 layout) ----
  const ushort* vbase = qkv + (size_t)b * Ss * QKV + 1024;
  const int e = 2 * t;   // elem in [0,512)
  float c0 = 0.f, c1 = 0.f;
#pragma unroll
  for (int n2 = 0; n2 < 32; ++n2) {
    const int src = (lane & 32) + n2;           // lane holding (this h, n2)
    const float a = __shfl(pn, src, 64);
    int row = __shfl(iv, src, 64);
    row = row < 0 ? 0 : row;                    // a == 0 if invalid
    const uint vvu = *reinterpret_cast<const uint*>(
        &vbase[(size_t)row * QKV + (e & 511)]);
    c0 += a * __uint_as_float(vvu << 16);
    c1 += a * __uint_as_float(vvu & 0xffff0000u);
  }
  const uint packed = (uint)f2b(c0) | ((uint)f2b(c1) << 16);
  *reinterpret_cast<uint*>(&ctx[(size_t)bs * 512 + e]) = packed;
}

// ---------------------------------------------------------------------------
// In-place row LayerNorm over DM=512. One wave per row, 4 rows per block.
// ---------------------------------------------------------------------------
__global__ __launch_bounds__(256) void ln_k(
    float* __restrict__ x, const float* __restrict__ g,
    const float* __restrict__ bta)
{
  const int w    = threadIdx.x >> 6;
  const int lane = threadIdx.x & 63;
  const int row  = blockIdx.x * 4 + w;

  float4* xr = reinterpret_cast<float4*>(x + (size_t)row * 512);
  const float4 v0 = xr[lane];
  const float4 v1 = xr[lane + 64];

  float sum = v0.x + v0.y + v0.z + v0.w + v1.x + v1.y + v1.z + v1.w;
  float sq  = v0.x * v0.x + v0.y * v0.y + v0.z * v0.z + v0.w * v0.w
            + v1.x * v1.x + v1.y * v1.y + v1.z * v1.z + v1.w * v1.w;
#pragma unroll
  for (int m = 32; m >= 1; m >>= 1) {
    sum += __shfl_xor(sum, m, 64);
    sq  += __shfl_xor(sq,  m, 64);
  }
  const float mu  = sum * (1.f / 512.f);
  const float var = sq * (1.f / 512.f) - mu * mu;
  const float rs  = rsqrtf(var + 1e-6f);

  const float4 g0 = reinterpret_cast<const float4*>(g)[lane];
  const float4 g1 = reinterpret_cast<const float4*>(g)[lane + 64];
  const float4 b0 = reinterpret_cast<const float4*>(bta)[lane];
  const float4 b1 = reinterpret_cast<const float4*>(bta)[lane + 64];

  float4 o0, o1;
  o0.x = (v0.x - mu) * rs * g0.x + b0.x;
  o0.y = (v0.y - mu) * rs * g0.y + b0.y;
  o0.z = (v0.z - mu) * rs * g0.z + b0.z;
  o0.w = (v0.w - mu) * rs * g0.w + b0.w;
  o1.x = (v1.x - mu) * rs * g1.x + b1.x;
  o1.y = (v1.y - mu) * rs * g1.y + b1.y;
  o1.z = (v1.z - mu) * rs * g1.z + b1.z;
  o1.w = (v1.w - mu) * rs * g1.w + b1.w;
  xr[lane]      = o0;
  xr[lane + 64] = o1;
}

extern "C" void kernel_launch(void* const* d_in, const int* in_sizes, int n_in,
                              void* d_out, int out_size, void* d_ws, size_t ws_size,
                              hipStream_t stream) {
  const float* hs  = (const float*)d_in[0];
  const float* rpe = (const float*)d_in[1];
  const int*   qkm = (const int*)d_in[2];
  const float* wq  = (const float*)d_in[4];
  const float* wk  = (const float*)d_in[5];
  const float* wv  = (const float*)d_in[6];
  const float* fcw = (const float*)d_in[7];
  const float* fcb = (const float*)d_in[8];
  const float* lng = (const float*)d_in[9];
  const float* lnb = (const float*)d_in[10];
  float* out = (float*)d_out;

  // workspace (ushort elems): Xb 2M | Wt3 0.75M | Wtf 0.25M | qkv 6M | cxb 2M
  ushort* Xb  = (ushort*)d_ws;
  ushort* Wt3 = Xb  + (size_t)Mm * DMm;
  ushort* Wtf = Wt3 + (size_t)3 * DMm * DMm;
  ushort* qkv = Wtf + (size_t)DMm * DMm;
  ushort* cxb = qkv + (size_t)Mm * QKV;

  cvt_bf16_k<<<(Mm * DMm / 8 + 255) / 256, 256, 0, stream>>>(hs, Xb, Mm * DMm / 8);
  cvt_wt_k<<<dim3(8, 8, 4), 256, 0, stream>>>(wq, wk, wv, fcw, Wt3, Wtf);

  // fused QKV: one GEMM, N = 1536
  gemm_mfma<1><<<dim3(Mm / 128, QKV / 64), 256, 0, stream>>>(
      Xb, Wt3, qkv, nullptr, nullptr, QKV);

  attn_k3<<<Mm, 256, 0, stream>>>(qkv, rpe, qkm, cxb);

  gemm_mfma<0><<<dim3(Mm / 128, DMm / 64), 256, 0, stream>>>(
      cxb, Wtf, out, fcb, hs, DMm);
  ln_k<<<Mm / 4, 256, 0, stream>>>(out, lng, lnb);
}

// Round 4
// 63.570 us; speedup vs baseline: 3.3110x; 1.0136x over previous
//
#include <hip/hip_runtime.h>
#include <hip/hip_bf16.h>

// (B, S, NK, H, D, DM) = (2, 2048, 32, 8, 64, 512)
constexpr int Bb  = 2;
constexpr int Ss  = 2048;
constexpr int NKk = 32;
constexpr int Hh  = 8;
constexpr int DMm = 512;
constexpr int Mm  = Bb * Ss;   // 4096 rows
constexpr int QKV = 1536;      // concat row stride

typedef __attribute__((ext_vector_type(8))) short bf16x8;
typedef __attribute__((ext_vector_type(4))) float f32x4;

__device__ __forceinline__ float b2f(unsigned short u) {
  return __uint_as_float((unsigned)u << 16);
}
__device__ __forceinline__ unsigned short f2b(float f) {
  unsigned u = __float_as_uint(f);
  unsigned r = (u + 0x7fffu + ((u >> 16) & 1u)) >> 16;   // RNE
  return (unsigned short)r;
}
__device__ __forceinline__ void gload_lds16(const ushort* g, ushort* l) {
  __builtin_amdgcn_global_load_lds(
      (const __attribute__((address_space(1))) void*)g,
      (__attribute__((address_space(3))) void*)l, 16, 0, 0);
}

// ---------------------------------------------------------------------------
// fp32 -> bf16 (flat), 8 elems/thread
// ---------------------------------------------------------------------------
__global__ __launch_bounds__(256) void cvt_bf16_k(
    const float* __restrict__ x, ushort* __restrict__ y, int n8)
{
  const int i = blockIdx.x * 256 + threadIdx.x;
  if (i >= n8) return;
  const float4 a = reinterpret_cast<const float4*>(x)[2 * i];
  const float4 b = reinterpret_cast<const float4*>(x)[2 * i + 1];
  ushort o[8] = {f2b(a.x), f2b(a.y), f2b(a.z), f2b(a.w),
                 f2b(b.x), f2b(b.y), f2b(b.z), f2b(b.w)};
  reinterpret_cast<uint4*>(y)[i] = *reinterpret_cast<uint4*>(o);
}

// ---------------------------------------------------------------------------
// Weight transpose+convert, all 4 weights in one launch (z = which weight).
// W fp32 [k][n] (512x512) -> Wt bf16 [n][k]
// ---------------------------------------------------------------------------
__global__ __launch_bounds__(256) void cvt_wt_k(
    const float* __restrict__ Wq, const float* __restrict__ Wk,
    const float* __restrict__ Wv, const float* __restrict__ Wf,
    ushort* __restrict__ Wt3, ushort* __restrict__ Wtf)
{
  __shared__ float tile[64][65];
  const int z = blockIdx.z;
  const float* W = (z == 0) ? Wq : (z == 1) ? Wk : (z == 2) ? Wv : Wf;
  ushort* Wt = (z < 3) ? (Wt3 + (size_t)z * 512 * 512) : Wtf;

  const int k0 = blockIdx.x * 64, n0 = blockIdx.y * 64;
  const int t = threadIdx.x;
#pragma unroll
  for (int p = 0; p < 4; ++p) {
    const int r = (t >> 4) + p * 16, c = (t & 15) * 4;
    const float4 v = *reinterpret_cast<const float4*>(&W[(size_t)(k0 + r) * 512 + n0 + c]);
    tile[r][c] = v.x; tile[r][c + 1] = v.y; tile[r][c + 2] = v.z; tile[r][c + 3] = v.w;
  }
  __syncthreads();
  const int n = t >> 2, ks = (t & 3) * 16;
  ushort o[16];
#pragma unroll
  for (int i = 0; i < 16; ++i) o[i] = f2b(tile[ks + i][n]);
  *reinterpret_cast<uint4*>(&Wt[(size_t)(n0 + n) * 512 + k0 + ks])     = *reinterpret_cast<uint4*>(&o[0]);
  *reinterpret_cast<uint4*>(&Wt[(size_t)(n0 + n) * 512 + k0 + ks + 8]) = *reinterpret_cast<uint4*>(&o[8]);
}

// ---------------------------------------------------------------------------
// m97-style bf16 MFMA GEMM: Y = Xb @ Wt^T (Xb: [M][512] bf16, Wt: [n][k] bf16)
// BM=128, BN=BNv (128 or 64), BK=64. 4 waves (2x2); wave tile 64 x BNv/2.
// Staging: global_load_lds width=16, SOURCE-swizzled 16B blocks
// (slot sb of row holds global block sb ^ (row&7)); ds_read applies the
// same XOR -> 2-way max bank aliasing (free, m136).
// OUT_BF16=1: bf16 out via LDS repack (smem reused). OUT_BF16=0: fp32 +
// bias + resid epilogue (fc).
// ---------------------------------------------------------------------------
template <int OUT_BF16, int BNv>
__global__ __launch_bounds__(256) void gemm_mfma2(
    const ushort* __restrict__ Xb, const ushort* __restrict__ Wt,
    void* __restrict__ Yv, const float* __restrict__ bias,
    const float* __restrict__ resid, int ldY)
{
  constexpr int NJ = BNv / 32;             // B-frags per wave
  constexpr int SMSZ = 8192 + BNv * 64;    // ushorts
  __shared__ ushort smem[SMSZ];
  ushort* As = smem;                       // [128][64] block-swizzled
  ushort* Bs = smem + 8192;                // [BNv][64] block-swizzled

  const int bm = blockIdx.x * 128;
  const int bn = blockIdx.y * BNv;
  const int t  = threadIdx.x;
  const int wave = t >> 6, lane = t & 63;
  const int wm = (wave >> 1) * 64;
  const int wn = (wave & 1) * (BNv / 2);

  f32x4 acc[4][NJ] = {};

  for (int k0 = 0; k0 < 512; k0 += 64) {
#pragma unroll
    for (int p = 0; p < 4; ++p) {          // A: 128x64 bf16 = 16 KB
      const int i = p * 256 + t;
      const int row = i >> 3, sb = i & 7;
      const ushort* g = Xb + (size_t)(bm + row) * 512 + k0 + ((sb ^ (row & 7)) << 3);
      gload_lds16(g, &As[(size_t)(p * 256 + wave * 64) * 8]);
    }
#pragma unroll
    for (int p = 0; p < NJ; ++p) {         // B: BNv x 64 bf16
      const int i = p * 256 + t;
      const int row = i >> 3, sb = i & 7;
      const ushort* g = Wt + (size_t)(bn + row) * 512 + k0 + ((sb ^ (row & 7)) << 3);
      gload_lds16(g, &Bs[(size_t)(p * 256 + wave * 64) * 8]);
    }
    __syncthreads();
#pragma unroll
    for (int ks = 0; ks < 2; ++ks) {
      const int kb = ks * 4 + (lane >> 4);
      bf16x8 af[4], bfr[NJ];
#pragma unroll
      for (int i = 0; i < 4; ++i) {
        const int row = wm + i * 16 + (lane & 15);
        af[i] = *reinterpret_cast<const bf16x8*>(&As[row * 64 + ((kb ^ (row & 7)) << 3)]);
      }
#pragma unroll
      for (int j = 0; j < NJ; ++j) {
        const int row = wn + j * 16 + (lane & 15);
        bfr[j] = *reinterpret_cast<const bf16x8*>(&Bs[row * 64 + ((kb ^ (row & 7)) << 3)]);
      }
#pragma unroll
      for (int i = 0; i < 4; ++i)
#pragma unroll
        for (int j = 0; j < NJ; ++j)
          acc[i][j] = __builtin_amdgcn_mfma_f32_16x16x32_bf16(af[i], bfr[j], acc[i][j], 0, 0, 0);
    }
    __syncthreads();
  }

  if (OUT_BF16) {
    // repack 128 x BNv bf16 tile through smem, then coalesced uint4 stores
#pragma unroll
    for (int i = 0; i < 4; ++i)
#pragma unroll
      for (int j = 0; j < NJ; ++j)
#pragma unroll
        for (int r = 0; r < 4; ++r) {
          const int row = wm + i * 16 + (lane >> 4) * 4 + r;
          const int col = wn + j * 16 + (lane & 15);
          smem[row * BNv + col] = f2b(acc[i][j][r]);
        }
    __syncthreads();
    ushort* Y = reinterpret_cast<ushort*>(Yv);
    constexpr int CPT = 128 * BNv / 8 / 256;   // uint4 chunks per thread
#pragma unroll
    for (int p = 0; p < CPT; ++p) {
      const int c = p * 256 + t;
      const int row = c / (BNv / 8);
      const int cb  = c % (BNv / 8);
      *reinterpret_cast<uint4*>(&Y[(size_t)(bm + row) * ldY + bn + cb * 8]) =
          *reinterpret_cast<uint4*>(&smem[row * BNv + cb * 8]);
    }
  } else {
    float* Y = reinterpret_cast<float*>(Yv);
#pragma unroll
    for (int i = 0; i < 4; ++i) {
#pragma unroll
      for (int j = 0; j < NJ; ++j) {
        const int m = bm + wm + i * 16 + (lane >> 4) * 4;
        const int n = bn + wn + j * 16 + (lane & 15);
        const float bb = bias[n];
#pragma unroll
        for (int r = 0; r < 4; ++r)
          Y[(size_t)(m + r) * ldY + n] = acc[i][j][r] + bb + resid[(size_t)(m + r) * 512 + n];
      }
    }
  }
}

// ---------------------------------------------------------------------------
// Sparse gather attention. One block per (b,s), 256 threads (4 waves).
// qkv layout: [b*S+s][1536] = q | k | v, bf16.
// ---------------------------------------------------------------------------
__global__ __launch_bounds__(256) void attn_k3(
    const ushort* __restrict__ qkv, const float* __restrict__ rpe,
    const int* __restrict__ qkm, ushort* __restrict__ ctx)
{
  __shared__ ushort Ks[32 * 512];   // row n at n*512, block-swizzled
  __shared__ float  qs[512];

  const int bs = blockIdx.x;
  const int b  = bs >> 11;
  const int s  = bs & 2047;
  const int t  = threadIdx.x;
  const int wv = t >> 6, lane = t & 63;

  const ushort* qrow = qkv + (size_t)bs * QKV;
  qs[t]       = b2f(qrow[t]);
  qs[t + 256] = b2f(qrow[t + 256]);

#pragma unroll
  for (int r = 0; r < 8; ++r) {
    const int n = r * 4 + wv;                 // wave-uniform row
    int im = qkm[s * NKk + n];
    im = im < 0 ? 0 : im;
    const ushort* gsrc = qkv + (size_t)(b * Ss + im) * QKV + 512
                       + ((lane ^ (n & 7)) * 8);
    gload_lds16(gsrc, &Ks[n * 512]);
  }

  int iv = qkm[s * NKk + (lane & 31)];

  __syncthreads();

  // ---- scores + softmax ----
  const int h = t >> 5;
  const int n = t & 31;
  const bool valid = (iv >= 0);

  float2 a2 = make_float2(0.f, 0.f);
#pragma unroll
  for (int j = 0; j < 8; ++j) {
    const int blk = (h * 8 + j) ^ (n & 7);
    const uint4 kk = *reinterpret_cast<const uint4*>(&Ks[n * 512 + blk * 8]);
    const float* qq = &qs[h * 64 + j * 8];
    a2.x += qq[0] * __uint_as_float(kk.x << 16);
    a2.y += qq[1] * __uint_as_float(kk.x & 0xffff0000u);
    a2.x += qq[2] * __uint_as_float(kk.y << 16);
    a2.y += qq[3] * __uint_as_float(kk.y & 0xffff0000u);
    a2.x += qq[4] * __uint_as_float(kk.z << 16);
    a2.y += qq[5] * __uint_as_float(kk.z & 0xffff0000u);
    a2.x += qq[6] * __uint_as_float(kk.w << 16);
    a2.y += qq[7] * __uint_as_float(kk.w & 0xffff0000u);
  }
  float sc = a2.x + a2.y + rpe[((size_t)bs * NKk + n) * Hh + h];
  sc = valid ? sc * 0.125f : -1e30f;

  float mx = sc;
#pragma unroll
  for (int m = 16; m >= 1; m >>= 1) mx = fmaxf(mx, __shfl_xor(mx, m, 32));
  const float p = valid ? __expf(sc - mx) : 0.f;
  float sum = p;
#pragma unroll
  for (int m = 16; m >= 1; m >>= 1) sum += __shfl_xor(sum, m, 32);
  const float pn = (sum > 0.f) ? (p / sum) : 0.f;

  // ---- ctx ----
  const ushort* vbase = qkv + (size_t)b * Ss * QKV + 1024;
  const int e = 2 * t;
  float c0 = 0.f, c1 = 0.f;
#pragma unroll
  for (int n2 = 0; n2 < 32; ++n2) {
    const int src = (lane & 32) + n2;
    const float a = __shfl(pn, src, 64);
    int row = __shfl(iv, src, 64);
    row = row < 0 ? 0 : row;
    const uint vvu = *reinterpret_cast<const uint*>(
        &vbase[(size_t)row * QKV + (e & 511)]);
    c0 += a * __uint_as_float(vvu << 16);
    c1 += a * __uint_as_float(vvu & 0xffff0000u);
  }
  const uint packed = (uint)f2b(c0) | ((uint)f2b(c1) << 16);
  *reinterpret_cast<uint*>(&ctx[(size_t)bs * 512 + e]) = packed;
}

// ---------------------------------------------------------------------------
// In-place row LayerNorm over DM=512. One wave per row, 4 rows per block.
// ---------------------------------------------------------------------------
__global__ __launch_bounds__(256) void ln_k(
    float* __restrict__ x, const float* __restrict__ g,
    const float* __restrict__ bta)
{
  const int w    = threadIdx.x >> 6;
  const int lane = threadIdx.x & 63;
  const int row  = blockIdx.x * 4 + w;

  float4* xr = reinterpret_cast<float4*>(x + (size_t)row * 512);
  const float4 v0 = xr[lane];
  const float4 v1 = xr[lane + 64];

  float sum = v0.x + v0.y + v0.z + v0.w + v1.x + v1.y + v1.z + v1.w;
  float sq  = v0.x * v0.x + v0.y * v0.y + v0.z * v0.z + v0.w * v0.w
            + v1.x * v1.x + v1.y * v1.y + v1.z * v1.z + v1.w * v1.w;
#pragma unroll
  for (int m = 32; m >= 1; m >>= 1) {
    sum += __shfl_xor(sum, m, 64);
    sq  += __shfl_xor(sq,  m, 64);
  }
  const float mu  = sum * (1.f / 512.f);
  const float var = sq * (1.f / 512.f) - mu * mu;
  const float rs  = rsqrtf(var + 1e-6f);

  const float4 g0 = reinterpret_cast<const float4*>(g)[lane];
  const float4 g1 = reinterpret_cast<const float4*>(g)[lane + 64];
  const float4 b0 = reinterpret_cast<const float4*>(bta)[lane];
  const float4 b1 = reinterpret_cast<const float4*>(bta)[lane + 64];

  float4 o0, o1;
  o0.x = (v0.x - mu) * rs * g0.x + b0.x;
  o0.y = (v0.y - mu) * rs * g0.y + b0.y;
  o0.z = (v0.z - mu) * rs * g0.z + b0.z;
  o0.w = (v0.w - mu) * rs * g0.w + b0.w;
  o1.x = (v1.x - mu) * rs * g1.x + b1.x;
  o1.y = (v1.y - mu) * rs * g1.y + b1.y;
  o1.z = (v1.z - mu) * rs * g1.z + b1.z;
  o1.w = (v1.w - mu) * rs * g1.w + b1.w;
  xr[lane]      = o0;
  xr[lane + 64] = o1;
}

extern "C" void kernel_launch(void* const* d_in, const int* in_sizes, int n_in,
                              void* d_out, int out_size, void* d_ws, size_t ws_size,
                              hipStream_t stream) {
  const float* hs  = (const float*)d_in[0];
  const float* rpe = (const float*)d_in[1];
  const int*   qkm = (const int*)d_in[2];
  const float* wq  = (const float*)d_in[4];
  const float* wk  = (const float*)d_in[5];
  const float* wv  = (const float*)d_in[6];
  const float* fcw = (const float*)d_in[7];
  const float* fcb = (const float*)d_in[8];
  const float* lng = (const float*)d_in[9];
  const float* lnb = (const float*)d_in[10];
  float* out = (float*)d_out;

  // workspace (ushort elems): Xb 2M | Wt3 0.75M | Wtf 0.25M | qkv 6M | cxb 2M
  ushort* Xb  = (ushort*)d_ws;
  ushort* Wt3 = Xb  + (size_t)Mm * DMm;
  ushort* Wtf = Wt3 + (size_t)3 * DMm * DMm;
  ushort* qkv = Wtf + (size_t)DMm * DMm;
  ushort* cxb = qkv + (size_t)Mm * QKV;

  cvt_bf16_k<<<(Mm * DMm / 8 + 255) / 256, 256, 0, stream>>>(hs, Xb, Mm * DMm / 8);
  cvt_wt_k<<<dim3(8, 8, 4), 256, 0, stream>>>(wq, wk, wv, fcw, Wt3, Wtf);

  // fused QKV GEMM: 128x128 tiles, 32x12 = 384 blocks
  gemm_mfma2<1, 128><<<dim3(Mm / 128, QKV / 128), 256, 0, stream>>>(
      Xb, Wt3, qkv, nullptr, nullptr, QKV);

  attn_k3<<<Mm, 256, 0, stream>>>(qkv, rpe, qkm, cxb);

  // fc GEMM: 128x64 tiles, 32x8 = 256 blocks (exact CU balance)
  gemm_mfma2<0, 64><<<dim3(Mm / 128, DMm / 64), 256, 0, stream>>>(
      cxb, Wtf, out, fcb, hs, DMm);
  ln_k<<<Mm / 4, 256, 0, stream>>>(out, lng, lnb);
}

// Round 5
// 54.973 us; speedup vs baseline: 3.8288x; 1.1564x over previous
//
#include <hip/hip_runtime.h>
#include <hip/hip_bf16.h>

// (B, S, NK, H, D, DM) = (2, 2048, 32, 8, 64, 512)
constexpr int Bb  = 2;
constexpr int Ss  = 2048;
constexpr int NKk = 32;
constexpr int Hh  = 8;
constexpr int DMm = 512;
constexpr int Mm  = Bb * Ss;   // 4096 rows
constexpr int QKV = 1536;      // concat row stride

typedef __attribute__((ext_vector_type(8))) short bf16x8;
typedef __attribute__((ext_vector_type(4))) float f32x4;

__device__ __forceinline__ float b2f(unsigned short u) {
  return __uint_as_float((unsigned)u << 16);
}
__device__ __forceinline__ unsigned short f2b(float f) {
  unsigned u = __float_as_uint(f);
  unsigned r = (u + 0x7fffu + ((u >> 16) & 1u)) >> 16;   // RNE
  return (unsigned short)r;
}
__device__ __forceinline__ void gload_lds16(const ushort* g, ushort* l) {
  __builtin_amdgcn_global_load_lds(
      (const __attribute__((address_space(1))) void*)g,
      (__attribute__((address_space(3))) void*)l, 16, 0, 0);
}

// ---------------------------------------------------------------------------
// Merged conversion kernel. grid (8,8,8), 256 threads.
//  z<4 : weight transpose+convert, W fp32 [k][n] (512x512) -> Wt bf16 [n][k]
//        (q/k/v into Wt3 rows {0..511,512..1023,1024..1535}, fc into Wtf)
//  z>=4: hs fp32 -> Xb bf16 flat; chunk id = (z-4)*64 + bx*8 + by, 8192 elems.
// ---------------------------------------------------------------------------
__global__ __launch_bounds__(256) void cvt_all_k(
    const float* __restrict__ hs,
    const float* __restrict__ Wq, const float* __restrict__ Wk,
    const float* __restrict__ Wv, const float* __restrict__ Wf,
    ushort* __restrict__ Xb, ushort* __restrict__ Wt3, ushort* __restrict__ Wtf)
{
  __shared__ float tile[64][65];
  const int z = blockIdx.z;
  const int t = threadIdx.x;

  if (z >= 4) {
    const int cid = (z - 4) * 64 + blockIdx.x * 8 + blockIdx.y;   // 0..255
    const size_t base8 = (size_t)cid * 1024;                      // uint4 units
#pragma unroll
    for (int it = 0; it < 4; ++it) {
      const size_t i = base8 + it * 256 + t;    // 8-elem chunk index
      const float4 a = reinterpret_cast<const float4*>(hs)[2 * i];
      const float4 b = reinterpret_cast<const float4*>(hs)[2 * i + 1];
      ushort o[8] = {f2b(a.x), f2b(a.y), f2b(a.z), f2b(a.w),
                     f2b(b.x), f2b(b.y), f2b(b.z), f2b(b.w)};
      reinterpret_cast<uint4*>(Xb)[i] = *reinterpret_cast<uint4*>(o);
    }
    return;
  }

  const float* W = (z == 0) ? Wq : (z == 1) ? Wk : (z == 2) ? Wv : Wf;
  ushort* Wt = (z < 3) ? (Wt3 + (size_t)z * 512 * 512) : Wtf;

  const int k0 = blockIdx.x * 64, n0 = blockIdx.y * 64;
#pragma unroll
  for (int p = 0; p < 4; ++p) {
    const int r = (t >> 4) + p * 16, c = (t & 15) * 4;
    const float4 v = *reinterpret_cast<const float4*>(&W[(size_t)(k0 + r) * 512 + n0 + c]);
    tile[r][c] = v.x; tile[r][c + 1] = v.y; tile[r][c + 2] = v.z; tile[r][c + 3] = v.w;
  }
  __syncthreads();
  const int n = t >> 2, ks = (t & 3) * 16;
  ushort o[16];
#pragma unroll
  for (int i = 0; i < 16; ++i) o[i] = f2b(tile[ks + i][n]);
  *reinterpret_cast<uint4*>(&Wt[(size_t)(n0 + n) * 512 + k0 + ks])     = *reinterpret_cast<uint4*>(&o[0]);
  *reinterpret_cast<uint4*>(&Wt[(size_t)(n0 + n) * 512 + k0 + ks + 8]) = *reinterpret_cast<uint4*>(&o[8]);
}

// ---------------------------------------------------------------------------
// 2-phase double-buffered bf16 MFMA GEMM (T3-minimum schedule):
//   prologue: STAGE(buf0,k=0); barrier
//   iter:     STAGE(buf^1,k+64) -> ds_read+MFMA(buf) -> barrier (vmcnt drain)
//   epilogue: compute last tile, no prefetch
// Y = Xb @ Wt^T. BM=128, BN=BNv (96 QKV / 64 fc), BK=64. 4 waves (2x2),
// wave tile 64 x BNv/2. Staging via global_load_lds w=16, SOURCE-swizzled
// 16B blocks (slot sb holds global block sb ^ (row&7)); reads apply same XOR.
// LDS: A 2x16KB + B 2x(BNv*128B) = 56 KB (BNv=96) -> 2 blocks/CU.
// ---------------------------------------------------------------------------
template <int OUT_BF16, int BNv>
__global__ __launch_bounds__(256) void gemm_dbuf(
    const ushort* __restrict__ Xb, const ushort* __restrict__ Wt,
    void* __restrict__ Yv, const float* __restrict__ bias,
    const float* __restrict__ resid, int ldY)
{
  constexpr int NJ = BNv / 32;                    // B-frags per wave
  __shared__ ushort smem[16384 + 2 * BNv * 64];   // A dbuf | B dbuf

  const int bm = blockIdx.x * 128;
  const int bn = blockIdx.y * BNv;
  const int t  = threadIdx.x;
  const int wave = t >> 6, lane = t & 63;
  const int wm = (wave >> 1) * 64;
  const int wn = (wave & 1) * (BNv / 2);

  f32x4 acc[4][NJ] = {};

  auto stage = [&](int buf, int k0) {
    ushort* A = smem + buf * 8192;
    ushort* B = smem + 16384 + buf * (BNv * 64);
#pragma unroll
    for (int p = 0; p < 4; ++p) {                 // A: 128x64 bf16
      const int i = p * 256 + t;
      const int row = i >> 3, sb = i & 7;
      gload_lds16(Xb + (size_t)(bm + row) * 512 + k0 + ((sb ^ (row & 7)) << 3),
                  &A[(size_t)(p * 256 + wave * 64) * 8]);
    }
#pragma unroll
    for (int p = 0; p < NJ; ++p) {                // B: BNv x 64 bf16
      const int i = p * 256 + t;
      const int row = i >> 3, sb = i & 7;
      gload_lds16(Wt + (size_t)(bn + row) * 512 + k0 + ((sb ^ (row & 7)) << 3),
                  &B[(size_t)(p * 256 + wave * 64) * 8]);
    }
  };

  auto compute = [&](int buf) {
    const ushort* A = smem + buf * 8192;
    const ushort* B = smem + 16384 + buf * (BNv * 64);
#pragma unroll
    for (int ks = 0; ks < 2; ++ks) {
      const int kb = ks * 4 + (lane >> 4);
      bf16x8 af[4], bfr[NJ];
#pragma unroll
      for (int i = 0; i < 4; ++i) {
        const int row = wm + i * 16 + (lane & 15);
        af[i] = *reinterpret_cast<const bf16x8*>(&A[row * 64 + ((kb ^ (row & 7)) << 3)]);
      }
#pragma unroll
      for (int j = 0; j < NJ; ++j) {
        const int row = wn + j * 16 + (lane & 15);
        bfr[j] = *reinterpret_cast<const bf16x8*>(&B[row * 64 + ((kb ^ (row & 7)) << 3)]);
      }
#pragma unroll
      for (int i = 0; i < 4; ++i)
#pragma unroll
        for (int j = 0; j < NJ; ++j)
          acc[i][j] = __builtin_amdgcn_mfma_f32_16x16x32_bf16(af[i], bfr[j], acc[i][j], 0, 0, 0);
    }
  };

  stage(0, 0);
  __syncthreads();                 // vmcnt(0) drain + barrier
  int cur = 0;
  for (int k0 = 64; k0 < 512; k0 += 64) {
    stage(cur ^ 1, k0);            // async loads fly under MFMA below
    compute(cur);
    __syncthreads();               // drains stage's vmcnt + all ds_reads
    cur ^= 1;
  }
  compute(cur);                    // last tile

  if (OUT_BF16) {
    __syncthreads();               // everyone done reading smem
#pragma unroll
    for (int i = 0; i < 4; ++i)
#pragma unroll
      for (int j = 0; j < NJ; ++j)
#pragma unroll
        for (int r = 0; r < 4; ++r) {
          const int row = wm + i * 16 + (lane >> 4) * 4 + r;
          const int col = wn + j * 16 + (lane & 15);
          smem[row * BNv + col] = f2b(acc[i][j][r]);
        }
    __syncthreads();
    ushort* Y = reinterpret_cast<ushort*>(Yv);
    constexpr int CPT = 128 * BNv / 8 / 256;   // uint4 chunks per thread
#pragma unroll
    for (int p = 0; p < CPT; ++p) {
      const int c = p * 256 + t;
      const int row = c / (BNv / 8);
      const int cb  = c % (BNv / 8);
      *reinterpret_cast<uint4*>(&Y[(size_t)(bm + row) * ldY + bn + cb * 8]) =
          *reinterpret_cast<uint4*>(&smem[row * BNv + cb * 8]);
    }
  } else {
    float* Y = reinterpret_cast<float*>(Yv);
#pragma unroll
    for (int i = 0; i < 4; ++i) {
#pragma unroll
      for (int j = 0; j < NJ; ++j) {
        const int m = bm + wm + i * 16 + (lane >> 4) * 4;
        const int n = bn + wn + j * 16 + (lane & 15);
        const float bb = bias[n];
#pragma unroll
        for (int r = 0; r < 4; ++r)
          Y[(size_t)(m + r) * ldY + n] = acc[i][j][r] + bb + resid[(size_t)(m + r) * 512 + n];
      }
    }
  }
}

// ---------------------------------------------------------------------------
// Sparse gather attention. One block per (b,s), 256 threads (4 waves).
// qkv layout: [b*S+s][1536] = q | k | v, bf16.
// ---------------------------------------------------------------------------
__global__ __launch_bounds__(256) void attn_k3(
    const ushort* __restrict__ qkv, const float* __restrict__ rpe,
    const int* __restrict__ qkm, ushort* __restrict__ ctx)
{
  __shared__ ushort Ks[32 * 512];   // row n at n*512, block-swizzled
  __shared__ float  qs[512];

  const int bs = blockIdx.x;
  const int b  = bs >> 11;
  const int s  = bs & 2047;
  const int t  = threadIdx.x;
  const int wv = t >> 6, lane = t & 63;

  const ushort* qrow = qkv + (size_t)bs * QKV;
  qs[t]       = b2f(qrow[t]);
  qs[t + 256] = b2f(qrow[t + 256]);

#pragma unroll
  for (int r = 0; r < 8; ++r) {
    const int n = r * 4 + wv;                 // wave-uniform row
    int im = qkm[s * NKk + n];
    im = im < 0 ? 0 : im;
    const ushort* gsrc = qkv + (size_t)(b * Ss + im) * QKV + 512
                       + ((lane ^ (n & 7)) * 8);
    gload_lds16(gsrc, &Ks[n * 512]);
  }

  int iv = qkm[s * NKk + (lane & 31)];

  __syncthreads();

  // ---- scores + softmax (thread = (h = t>>5, n = t&31)) ----
  const int h = t >> 5;
  const int n = t & 31;
  const bool valid = (iv >= 0);

  float2 a2 = make_float2(0.f, 0.f);
#pragma unroll
  for (int j = 0; j < 8; ++j) {
    const int blk = (h * 8 + j) ^ (n & 7);
    const uint4 kk = *reinterpret_cast<const uint4*>(&Ks[n * 512 + blk * 8]);
    const float* qq = &qs[h * 64 + j * 8];
    a2.x += qq[0] * __uint_as_float(kk.x << 16);
    a2.y += qq[1] * __uint_as_float(kk.x & 0xffff0000u);
    a2.x += qq[2] * __uint_as_float(kk.y << 16);
    a2.y += qq[3] * __uint_as_float(kk.y & 0xffff0000u);
    a2.x += qq[4] * __uint_as_float(kk.z << 16);
    a2.y += qq[5] * __uint_as_float(kk.z & 0xffff0000u);
    a2.x += qq[6] * __uint_as_float(kk.w << 16);
    a2.y += qq[7] * __uint_as_float(kk.w & 0xffff0000u);
  }
  float sc = a2.x + a2.y + rpe[((size_t)bs * NKk + n) * Hh + h];
  sc = valid ? sc * 0.125f : -1e30f;

  float mx = sc;
#pragma unroll
  for (int m = 16; m >= 1; m >>= 1) mx = fmaxf(mx, __shfl_xor(mx, m, 32));
  const float p = valid ? __expf(sc - mx) : 0.f;
  float sum = p;
#pragma unroll
  for (int m = 16; m >= 1; m >>= 1) sum += __shfl_xor(sum, m, 32);
  const float pn = (sum > 0.f) ? (p / sum) : 0.f;

  // ---- ctx elems 2t, 2t+1 ----
  const ushort* vbase = qkv + (size_t)b * Ss * QKV + 1024;
  const int e = 2 * t;
  float c0 = 0.f, c1 = 0.f;
#pragma unroll
  for (int n2 = 0; n2 < 32; ++n2) {
    const int src = (lane & 32) + n2;
    const float a = __shfl(pn, src, 64);
    int row = __shfl(iv, src, 64);
    row = row < 0 ? 0 : row;
    const uint vvu = *reinterpret_cast<const uint*>(
        &vbase[(size_t)row * QKV + (e & 511)]);
    c0 += a * __uint_as_float(vvu << 16);
    c1 += a * __uint_as_float(vvu & 0xffff0000u);
  }
  const uint packed = (uint)f2b(c0) | ((uint)f2b(c1) << 16);
  *reinterpret_cast<uint*>(&ctx[(size_t)bs * 512 + e]) = packed;
}

// ---------------------------------------------------------------------------
// In-place row LayerNorm over DM=512. One wave per row, 4 rows per block.
// ---------------------------------------------------------------------------
__global__ __launch_bounds__(256) void ln_k(
    float* __restrict__ x, const float* __restrict__ g,
    const float* __restrict__ bta)
{
  const int w    = threadIdx.x >> 6;
  const int lane = threadIdx.x & 63;
  const int row  = blockIdx.x * 4 + w;

  float4* xr = reinterpret_cast<float4*>(x + (size_t)row * 512);
  const float4 v0 = xr[lane];
  const float4 v1 = xr[lane + 64];

  float sum = v0.x + v0.y + v0.z + v0.w + v1.x + v1.y + v1.z + v1.w;
  float sq  = v0.x * v0.x + v0.y * v0.y + v0.z * v0.z + v0.w * v0.w
            + v1.x * v1.x + v1.y * v1.y + v1.z * v1.z + v1.w * v1.w;
#pragma unroll
  for (int m = 32; m >= 1; m >>= 1) {
    sum += __shfl_xor(sum, m, 64);
    sq  += __shfl_xor(sq,  m, 64);
  }
  const float mu  = sum * (1.f / 512.f);
  const float var = sq * (1.f / 512.f) - mu * mu;
  const float rs  = rsqrtf(var + 1e-6f);

  const float4 g0 = reinterpret_cast<const float4*>(g)[lane];
  const float4 g1 = reinterpret_cast<const float4*>(g)[lane + 64];
  const float4 b0 = reinterpret_cast<const float4*>(bta)[lane];
  const float4 b1 = reinterpret_cast<const float4*>(bta)[lane + 64];

  float4 o0, o1;
  o0.x = (v0.x - mu) * rs * g0.x + b0.x;
  o0.y = (v0.y - mu) * rs * g0.y + b0.y;
  o0.z = (v0.z - mu) * rs * g0.z + b0.z;
  o0.w = (v0.w - mu) * rs * g0.w + b0.w;
  o1.x = (v1.x - mu) * rs * g1.x + b1.x;
  o1.y = (v1.y - mu) * rs * g1.y + b1.y;
  o1.z = (v1.z - mu) * rs * g1.z + b1.z;
  o1.w = (v1.w - mu) * rs * g1.w + b1.w;
  xr[lane]      = o0;
  xr[lane + 64] = o1;
}

extern "C" void kernel_launch(void* const* d_in, const int* in_sizes, int n_in,
                              void* d_out, int out_size, void* d_ws, size_t ws_size,
                              hipStream_t stream) {
  const float* hs  = (const float*)d_in[0];
  const float* rpe = (const float*)d_in[1];
  const int*   qkm = (const int*)d_in[2];
  const float* wq  = (const float*)d_in[4];
  const float* wk  = (const float*)d_in[5];
  const float* wv  = (const float*)d_in[6];
  const float* fcw = (const float*)d_in[7];
  const float* fcb = (const float*)d_in[8];
  const float* lng = (const float*)d_in[9];
  const float* lnb = (const float*)d_in[10];
  float* out = (float*)d_out;

  // workspace (ushort elems): Xb 2M | Wt3 0.75M | Wtf 0.25M | qkv 6M | cxb 2M
  ushort* Xb  = (ushort*)d_ws;
  ushort* Wt3 = Xb  + (size_t)Mm * DMm;
  ushort* Wtf = Wt3 + (size_t)3 * DMm * DMm;
  ushort* qkv = Wtf + (size_t)DMm * DMm;
  ushort* cxb = qkv + (size_t)Mm * QKV;

  // all conversions in one launch: z<4 weights, z>=4 hs->bf16
  cvt_all_k<<<dim3(8, 8, 8), 256, 0, stream>>>(hs, wq, wk, wv, fcw, Xb, Wt3, Wtf);

  // fused QKV GEMM: 128x96 tiles -> 32x16 = 512 blocks = 2.00/CU exact
  gemm_dbuf<1, 96><<<dim3(Mm / 128, QKV / 96), 256, 0, stream>>>(
      Xb, Wt3, qkv, nullptr, nullptr, QKV);

  attn_k3<<<Mm, 256, 0, stream>>>(qkv, rpe, qkm, cxb);

  // fc GEMM: 128x64 tiles -> 32x8 = 256 blocks = 1.00/CU exact
  gemm_dbuf<0, 64><<<dim3(Mm / 128, DMm / 64), 256, 0, stream>>>(
      cxb, Wtf, out, fcb, hs, DMm);
  ln_k<<<Mm / 4, 256, 0, stream>>>(out, lng, lnb);
}